// Round 2
// baseline (329.214 us; speedup 1.0000x reference)
//
#include <hip/hip_runtime.h>
#include <hip/hip_bf16.h>

typedef __hip_bfloat16 bf16;
typedef __attribute__((ext_vector_type(8))) __bf16 bf16x8;
typedef __attribute__((ext_vector_type(8))) short s16x8;
typedef __attribute__((ext_vector_type(4))) float f32x4;

#define AS1 __attribute__((address_space(1)))
#define AS3 __attribute__((address_space(3)))

#define DDIM 2048
#define CCOLS 128   // 0..15 shared, 16..111 routed (e=(c-16)>>4, r=(c-16)&15), 112..127 zero pad
#define TTOK 16384

// ---------------- K0: fp32->bf16 convert of x + fp32 router (logits, softmax, top-2) ----------------

__global__ __launch_bounds__(256) void conv_router_kernel(
    const float* __restrict__ x, const float* __restrict__ Wr, const float* __restrict__ br,
    bf16* __restrict__ xb, float* __restrict__ gates) {
  int t = blockIdx.x;
  int tid = threadIdx.x;
  long base = (long)t * DDIM + tid * 8;
  f32x4 v0 = *(const f32x4*)(x + base);
  f32x4 v1 = *(const f32x4*)(x + base + 4);
  float xv[8];
#pragma unroll
  for (int j = 0; j < 4; ++j) { xv[j] = v0[j]; xv[4 + j] = v1[j]; }
  __align__(16) bf16 tmp[8];
#pragma unroll
  for (int j = 0; j < 8; ++j) tmp[j] = __float2bfloat16(xv[j]);
  *(s16x8*)(xb + base) = *(const s16x8*)tmp;

  // fp32 router partial dots
  float p[6] = {0.f, 0.f, 0.f, 0.f, 0.f, 0.f};
  int d0 = tid * 8;
#pragma unroll
  for (int j = 0; j < 8; ++j) {
    const float* wrow = Wr + (d0 + j) * 6;
#pragma unroll
    for (int e = 0; e < 6; ++e) p[e] += xv[j] * wrow[e];
  }
#pragma unroll
  for (int off = 32; off > 0; off >>= 1)
#pragma unroll
    for (int e = 0; e < 6; ++e) p[e] += __shfl_down(p[e], off);
  __shared__ float red[4][6];
  int wave = tid >> 6, lane = tid & 63;
  if (lane == 0)
#pragma unroll
    for (int e = 0; e < 6; ++e) red[wave][e] = p[e];
  __syncthreads();
  if (tid == 0) {
    float g[6], mx = -1e30f;
#pragma unroll
    for (int e = 0; e < 6; ++e) {
      g[e] = red[0][e] + red[1][e] + red[2][e] + red[3][e] + br[e];
      mx = fmaxf(mx, g[e]);
    }
    float s = 0.f;
#pragma unroll
    for (int e = 0; e < 6; ++e) { g[e] = __expf(g[e] - mx); s += g[e]; }
    float inv = 1.f / s;
#pragma unroll
    for (int e = 0; e < 6; ++e) g[e] *= inv;
    int i1 = 0; float w1 = g[0];
#pragma unroll
    for (int e = 1; e < 6; ++e) if (g[e] > w1) { w1 = g[e]; i1 = e; }
    int i2 = -1; float w2 = -1.f;
#pragma unroll
    for (int e = 0; e < 6; ++e) if (e != i1 && g[e] > w2) { w2 = g[e]; i2 = e; }
#pragma unroll
    for (int e = 0; e < 6; ++e)
      gates[(long)t * 6 + e] = (e == i1) ? w1 : (e == i2) ? w2 : 0.f;
  }
}

// ---------------- prep: W_base^T (fp32 -> bf16), A_cat^T, B_cat^T ----------------

__global__ __launch_bounds__(256) void convert_WT_kernel(const float* __restrict__ W,
                                                         bf16* __restrict__ WT) {
  __shared__ bf16 tl[64][65];
  int bi = blockIdx.x >> 5, bj = blockIdx.x & 31;
  int k0 = bi * 64, n0 = bj * 64;
  int tid = threadIdx.x;
  int r = tid >> 2, c0 = (tid & 3) << 4;
#pragma unroll
  for (int q = 0; q < 4; ++q) {
    f32x4 v = *(const f32x4*)(W + (long)(k0 + r) * DDIM + n0 + c0 + q * 4);
#pragma unroll
    for (int j = 0; j < 4; ++j) tl[r][c0 + q * 4 + j] = __float2bfloat16(v[j]);
  }
  __syncthreads();
  __align__(16) bf16 o[16];
#pragma unroll
  for (int i = 0; i < 16; ++i) o[i] = tl[c0 + i][r];
  *(s16x8*)(WT + (long)(n0 + r) * DDIM + k0 + c0) = *(const s16x8*)o;
  *(s16x8*)(WT + (long)(n0 + r) * DDIM + k0 + c0 + 8) = *(const s16x8*)(o + 8);
}

__global__ void build_AcatT(const float* __restrict__ A_s, const float* __restrict__ A_r,
                            bf16* __restrict__ AcT) {
  int idx = blockIdx.x * 256 + threadIdx.x;           // over 128*2048
  int c = idx >> 11, d = idx & 2047;
  float v = 0.f;
  if (c < 16)       v = A_s[d * 16 + c];
  else if (c < 112) { int cr = c - 16; v = A_r[((long)(cr >> 4) * DDIM + d) * 16 + (cr & 15)]; }
  AcT[(long)c * DDIM + d] = __float2bfloat16(v);
}

__global__ void build_BcatT(const float* __restrict__ B_s, const float* __restrict__ B_r,
                            bf16* __restrict__ BcT) {
  int idx = blockIdx.x * 256 + threadIdx.x;           // over 2048*128
  int n = idx >> 7, c = idx & 127;
  float v = 0.f;
  if (c < 16)       v = B_s[c * DDIM + n];
  else if (c < 112) v = B_r[(long)(c - 16) * DDIM + n];
  BcT[(long)n * CCOLS + c] = __float2bfloat16(v);
}

// ---------------- staging: [ROWS x 64] bf16 tile, LDS-linear, via global_load_lds ----------------

template <int ROWS>
__device__ __forceinline__ void stage_tile(const bf16* __restrict__ g, long rs,
                                           bf16* lds, int wave, int lane) {
#pragma unroll
  for (int i = 0; i < (ROWS >> 5); ++i) {
    int chunk_base = (i * 4 + wave) * 64;             // 16B chunks, wave-uniform LDS base
    int byte = (chunk_base + lane) * 16;
    int row = byte >> 7;                              // 128B per tile row
    int col = (byte & 127) >> 1;
    __builtin_amdgcn_global_load_lds(
        (const AS1 void*)(g + (long)row * rs + col),
        (AS3 void*)(lds + chunk_base * 8), 16, 0, 0);
  }
}

// ---------------- kernel A: H = xb @ A_cat, apply fp32 gates, emit hw ----------------

__global__ __launch_bounds__(256) void lora_kernel(
    const bf16* __restrict__ xb, const bf16* __restrict__ AcT,
    const float* __restrict__ gates, bf16* __restrict__ hw) {
  __shared__ __align__(16) short smem[(64 + 128) * 64];
  __shared__ float G[64][6];
  bf16* X_s = (bf16*)smem;
  bf16* B_s = (bf16*)(smem + 64 * 64);
  int tid = threadIdx.x, wave = tid >> 6, lane = tid & 63;
  long m0 = (long)blockIdx.x * 64;
  for (int i = tid; i < 384; i += 256) G[i / 6][i % 6] = gates[(m0 + i / 6) * 6 + i % 6];

  f32x4 acc[7];
#pragma unroll
  for (int i = 0; i < 7; ++i) acc[i] = f32x4{0.f, 0.f, 0.f, 0.f};

  for (int kt = 0; kt < 32; ++kt) {
    int k0 = kt * 64;
    stage_tile<64>(xb + m0 * DDIM + k0, DDIM, X_s, wave, lane);
    stage_tile<128>(AcT + k0, DDIM, B_s, wave, lane);
    __syncthreads();
#pragma unroll
    for (int kk = 0; kk < 2; ++kk) {
      bf16x8 a = *(const bf16x8*)(X_s + (16 * wave + (lane & 15)) * 64 + kk * 32 + (lane >> 4) * 8);
#pragma unroll
      for (int nr = 0; nr < 7; ++nr) {
        bf16x8 b = *(const bf16x8*)(B_s + (16 * nr + (lane & 15)) * 64 + kk * 32 + (lane >> 4) * 8);
        acc[nr] = __builtin_amdgcn_mfma_f32_16x16x32_bf16(a, b, acc[nr], 0, 0, 0);
      }
    }
    __syncthreads();
  }

#pragma unroll
  for (int nr = 0; nr < 7; ++nr) {
    int c = nr * 16 + (lane & 15);
#pragma unroll
    for (int reg = 0; reg < 4; ++reg) {
      int tl = 16 * wave + 4 * (lane >> 4) + reg;
      float wgt = (c < 16) ? 1.f : G[tl][(c - 16) >> 4];
      hw[(m0 + tl) * CCOLS + c] = __float2bfloat16(acc[nr][reg] * wgt);
    }
  }
  { // zero pad cols 112..127
    int c = 112 + (lane & 15);
#pragma unroll
    for (int reg = 0; reg < 4; ++reg) {
      int tl = 16 * wave + 4 * (lane >> 4) + reg;
      hw[(m0 + tl) * CCOLS + c] = __float2bfloat16(0.f);
    }
  }
}

// ---------------- kernel B: out = xb@W^T + b + hw@B_cat, fp32 out (K extended to 2176) ----------------

__global__ __launch_bounds__(256) void main_gemm_kernel(
    const bf16* __restrict__ xb, const bf16* __restrict__ WT,
    const bf16* __restrict__ hw, const bf16* __restrict__ BcT,
    const float* __restrict__ b_base, float* __restrict__ out) {
  __shared__ __align__(16) short smem[2 * 128 * 64];
  bf16* A_s = (bf16*)smem;
  bf16* B_s = (bf16*)(smem + 128 * 64);
  int tid = threadIdx.x, wave = tid >> 6, lane = tid & 63;
  int wr = wave >> 1, wc = wave & 1;

  // XCD-bijective swizzle (nwg = 2048, divisible by 8)
  int bid = blockIdx.x;
  int cpx = gridDim.x >> 3;
  int swz = (bid & 7) * cpx + (bid >> 3);
  int bm = swz >> 4, bn = swz & 15;                   // 128 x 16 grid
  long m0 = (long)bm * 128;
  int n0 = bn * 128;

  f32x4 acc[4][4];
#pragma unroll
  for (int i = 0; i < 4; ++i)
#pragma unroll
    for (int j = 0; j < 4; ++j) acc[i][j] = f32x4{0.f, 0.f, 0.f, 0.f};

  for (int kt = 0; kt < 34; ++kt) {
    const bf16 *Ab, *Bb; long sa, sb; int k0;
    if (kt < 32) { Ab = xb; sa = DDIM;  Bb = WT;  sb = DDIM;  k0 = kt * 64; }
    else         { Ab = hw; sa = CCOLS; Bb = BcT; sb = CCOLS; k0 = (kt - 32) * 64; }
    stage_tile<128>(Ab + m0 * sa + k0, sa, A_s, wave, lane);
    stage_tile<128>(Bb + (long)n0 * sb + k0, sb, B_s, wave, lane);
    __syncthreads();
#pragma unroll
    for (int kk = 0; kk < 2; ++kk) {
      bf16x8 a[4], b[4];
#pragma unroll
      for (int mr = 0; mr < 4; ++mr)
        a[mr] = *(const bf16x8*)(A_s + (64 * wr + 16 * mr + (lane & 15)) * 64 + kk * 32 + (lane >> 4) * 8);
#pragma unroll
      for (int nr = 0; nr < 4; ++nr)
        b[nr] = *(const bf16x8*)(B_s + (64 * wc + 16 * nr + (lane & 15)) * 64 + kk * 32 + (lane >> 4) * 8);
#pragma unroll
      for (int mr = 0; mr < 4; ++mr)
#pragma unroll
        for (int nr = 0; nr < 4; ++nr)
          acc[mr][nr] = __builtin_amdgcn_mfma_f32_16x16x32_bf16(a[mr], b[nr], acc[mr][nr], 0, 0, 0);
    }
    __syncthreads();
  }

  // epilogue: bias add, two-pass fp32 LDS repack (64x128 f32 = 32KB reuses smem), float4 stores
  float bias[4];
#pragma unroll
  for (int nr = 0; nr < 4; ++nr) bias[nr] = b_base[n0 + 64 * wc + 16 * nr + (lane & 15)];
  float* Cs = (float*)smem;
#pragma unroll
  for (int p = 0; p < 2; ++p) {
    __syncthreads();
#pragma unroll
    for (int mh = 0; mh < 2; ++mh) {
      int mr = 2 * p + mh;
#pragma unroll
      for (int nr = 0; nr < 4; ++nr) {
        int cl = 64 * wc + 16 * nr + (lane & 15);
#pragma unroll
        for (int reg = 0; reg < 4; ++reg) {
          int lr = 32 * wr + 16 * mh + 4 * (lane >> 4) + reg;
          Cs[lr * 128 + cl] = acc[mr][nr][reg] + bias[nr];
        }
      }
    }
    __syncthreads();
#pragma unroll 2
    for (int q = tid; q < 64 * 128 / 4; q += 256) {
      int lr = q >> 5;
      int c4 = (q & 31) << 2;
      long gr = m0 + 64 * (lr >> 5) + 32 * p + 16 * ((lr >> 4) & 1) + (lr & 15);
      *(f32x4*)(out + gr * DDIM + n0 + c4) = *(const f32x4*)(Cs + lr * 128 + c4);
    }
  }
}

// ---------------- launcher ----------------

extern "C" void kernel_launch(void* const* d_in, const int* in_sizes, int n_in,
                              void* d_out, int out_size, void* d_ws, size_t ws_size,
                              hipStream_t stream) {
  const float* x        = (const float*)d_in[0];
  const float* W_base   = (const float*)d_in[1];
  const float* b_base   = (const float*)d_in[2];
  const float* A_s      = (const float*)d_in[3];
  const float* B_s      = (const float*)d_in[4];
  const float* A_r      = (const float*)d_in[5];
  const float* B_r      = (const float*)d_in[6];
  const float* W_router = (const float*)d_in[7];
  const float* b_router = (const float*)d_in[8];
  float* out = (float*)d_out;

  char* ws = (char*)d_ws;
  bf16*  xb    = (bf16*)(ws);                    // 16384*2048*2 = 67,108,864 B
  bf16*  WT    = (bf16*)(ws + 67108864);         //  2048*2048*2 =  8,388,608 B
  bf16*  AcT   = (bf16*)(ws + 75497472);         //   128*2048*2 =    524,288 B
  bf16*  BcT   = (bf16*)(ws + 76021760);         //   2048*128*2 =    524,288 B
  bf16*  hw    = (bf16*)(ws + 76546048);         //  16384*128*2 =  4,194,304 B
  float* gates = (float*)(ws + 80740352);        //   16384*6*4  =    393,216 B  (total ~81.1 MB)

  conv_router_kernel<<<TTOK, 256, 0, stream>>>(x, W_router, b_router, xb, gates);
  convert_WT_kernel<<<1024, 256, 0, stream>>>(W_base, WT);
  build_AcatT<<<1024, 256, 0, stream>>>(A_s, A_r, AcT);
  build_BcatT<<<1024, 256, 0, stream>>>(B_s, B_r, BcT);
  lora_kernel<<<256, 256, 0, stream>>>(xb, AcT, gates, hw);
  main_gemm_kernel<<<2048, 256, 0, stream>>>(xb, WT, hw, BcT, b_base, out);
}

// Round 3
// 287.191 us; speedup vs baseline: 1.1463x; 1.1463x over previous
//
#include <hip/hip_runtime.h>
#include <hip/hip_bf16.h>

typedef __hip_bfloat16 bf16;
typedef __attribute__((ext_vector_type(8))) __bf16 bf16x8;
typedef __attribute__((ext_vector_type(8))) short s16x8;
typedef __attribute__((ext_vector_type(4))) float f32x4;

#define AS1 __attribute__((address_space(1)))
#define AS3 __attribute__((address_space(3)))

#define DDIM 2048
#define KDIM 2176   // 2048 (x @ W^T) + 128 (hw @ B_cat) fused K-extension
#define CCOLS 128   // 0..15 shared, 16..111 routed, 112..127 zero pad
#define TTOK 16384
#define NT 68       // K tiles of 32

// ---------------- K0: fp32->bf16 convert of x + fp32 router (logits, softmax, top-2) ----------------

__global__ __launch_bounds__(256) void conv_router_kernel(
    const float* __restrict__ x, const float* __restrict__ Wr, const float* __restrict__ br,
    bf16* __restrict__ xh, float* __restrict__ gates) {
  int t = blockIdx.x;
  int tid = threadIdx.x;
  f32x4 v0 = *(const f32x4*)(x + (long)t * DDIM + tid * 8);
  f32x4 v1 = *(const f32x4*)(x + (long)t * DDIM + tid * 8 + 4);
  float xv[8];
#pragma unroll
  for (int j = 0; j < 4; ++j) { xv[j] = v0[j]; xv[4 + j] = v1[j]; }
  __align__(16) bf16 tmp[8];
#pragma unroll
  for (int j = 0; j < 8; ++j) tmp[j] = __float2bfloat16(xv[j]);
  *(s16x8*)(xh + (long)t * KDIM + tid * 8) = *(const s16x8*)tmp;

  float p[6] = {0.f, 0.f, 0.f, 0.f, 0.f, 0.f};
  int d0 = tid * 8;
#pragma unroll
  for (int j = 0; j < 8; ++j) {
    const float* wrow = Wr + (d0 + j) * 6;
#pragma unroll
    for (int e = 0; e < 6; ++e) p[e] += xv[j] * wrow[e];
  }
#pragma unroll
  for (int off = 32; off > 0; off >>= 1)
#pragma unroll
    for (int e = 0; e < 6; ++e) p[e] += __shfl_down(p[e], off);
  __shared__ float red[4][6];
  int wave = tid >> 6, lane = tid & 63;
  if (lane == 0)
#pragma unroll
    for (int e = 0; e < 6; ++e) red[wave][e] = p[e];
  __syncthreads();
  if (tid == 0) {
    float g[6], mx = -1e30f;
#pragma unroll
    for (int e = 0; e < 6; ++e) {
      g[e] = red[0][e] + red[1][e] + red[2][e] + red[3][e] + br[e];
      mx = fmaxf(mx, g[e]);
    }
    float s = 0.f;
#pragma unroll
    for (int e = 0; e < 6; ++e) { g[e] = __expf(g[e] - mx); s += g[e]; }
    float inv = 1.f / s;
#pragma unroll
    for (int e = 0; e < 6; ++e) g[e] *= inv;
    int i1 = 0; float w1 = g[0];
#pragma unroll
    for (int e = 1; e < 6; ++e) if (g[e] > w1) { w1 = g[e]; i1 = e; }
    int i2 = -1; float w2 = -1.f;
#pragma unroll
    for (int e = 0; e < 6; ++e) if (e != i1 && g[e] > w2) { w2 = g[e]; i2 = e; }
#pragma unroll
    for (int e = 0; e < 6; ++e)
      gates[(long)t * 6 + e] = (e == i1) ? w1 : (e == i2) ? w2 : 0.f;
  }
}

// ---------------- prep: W_base^T -> Wcat[:, :2048], B_cat^T -> Wcat[:, 2048:], A_cat^T ----------------

__global__ __launch_bounds__(256) void convert_WT_kernel(const float* __restrict__ W,
                                                         bf16* __restrict__ Wcat) {
  __shared__ bf16 tl[64][65];
  int bi = blockIdx.x >> 5, bj = blockIdx.x & 31;
  int k0 = bi * 64, n0 = bj * 64;
  int tid = threadIdx.x;
  int r = tid >> 2, c0 = (tid & 3) << 4;
#pragma unroll
  for (int q = 0; q < 4; ++q) {
    f32x4 v = *(const f32x4*)(W + (long)(k0 + r) * DDIM + n0 + c0 + q * 4);
#pragma unroll
    for (int j = 0; j < 4; ++j) tl[r][c0 + q * 4 + j] = __float2bfloat16(v[j]);
  }
  __syncthreads();
  __align__(16) bf16 o[16];
#pragma unroll
  for (int i = 0; i < 16; ++i) o[i] = tl[c0 + i][r];
  *(s16x8*)(Wcat + (long)(n0 + r) * KDIM + k0 + c0) = *(const s16x8*)o;
  *(s16x8*)(Wcat + (long)(n0 + r) * KDIM + k0 + c0 + 8) = *(const s16x8*)(o + 8);
}

__global__ void build_AcatT(const float* __restrict__ A_s, const float* __restrict__ A_r,
                            bf16* __restrict__ AcT) {
  int idx = blockIdx.x * 256 + threadIdx.x;           // over 128*2048
  int c = idx >> 11, d = idx & 2047;
  float v = 0.f;
  if (c < 16)       v = A_s[d * 16 + c];
  else if (c < 112) { int cr = c - 16; v = A_r[((long)(cr >> 4) * DDIM + d) * 16 + (cr & 15)]; }
  AcT[(long)c * DDIM + d] = __float2bfloat16(v);
}

__global__ void build_BcatT(const float* __restrict__ B_s, const float* __restrict__ B_r,
                            bf16* __restrict__ Wcat) {
  int idx = blockIdx.x * 256 + threadIdx.x;           // over 2048*128
  int n = idx >> 7, c = idx & 127;
  float v = 0.f;
  if (c < 16)       v = B_s[c * DDIM + n];
  else if (c < 112) v = B_r[(long)(c - 16) * DDIM + n];
  Wcat[(long)n * KDIM + 2048 + c] = __float2bfloat16(v);
}

// ---------------- staging: [ROWS x 64] bf16 tile, LDS-linear (lora kernel) ----------------

template <int ROWS>
__device__ __forceinline__ void stage_tile(const bf16* __restrict__ g, long rs,
                                           bf16* lds, int wave, int lane) {
#pragma unroll
  for (int i = 0; i < (ROWS >> 5); ++i) {
    int chunk_base = (i * 4 + wave) * 64;
    int byte = (chunk_base + lane) * 16;
    int row = byte >> 7;
    int col = (byte & 127) >> 1;
    __builtin_amdgcn_global_load_lds(
        (const AS1 void*)(g + (long)row * rs + col),
        (AS3 void*)(lds + chunk_base * 8), 16, 0, 0);
  }
}

// ---------------- kernel A: H = xb @ A_cat, apply fp32 gates, write into xh[:, 2048:] ----------------

__global__ __launch_bounds__(256) void lora_kernel(
    bf16* __restrict__ xh, const bf16* __restrict__ AcT,
    const float* __restrict__ gates) {
  __shared__ __align__(16) short smem[(64 + 128) * 64];
  __shared__ float G[64][6];
  bf16* X_s = (bf16*)smem;
  bf16* B_s = (bf16*)(smem + 64 * 64);
  int tid = threadIdx.x, wave = tid >> 6, lane = tid & 63;
  long m0 = (long)blockIdx.x * 64;
  for (int i = tid; i < 384; i += 256) G[i / 6][i % 6] = gates[(m0 + i / 6) * 6 + i % 6];

  f32x4 acc[7];
#pragma unroll
  for (int i = 0; i < 7; ++i) acc[i] = f32x4{0.f, 0.f, 0.f, 0.f};

  for (int kt = 0; kt < 32; ++kt) {
    int k0 = kt * 64;
    stage_tile<64>(xh + m0 * KDIM + k0, KDIM, X_s, wave, lane);
    stage_tile<128>(AcT + k0, DDIM, B_s, wave, lane);
    __syncthreads();
#pragma unroll
    for (int kk = 0; kk < 2; ++kk) {
      bf16x8 a = *(const bf16x8*)(X_s + (16 * wave + (lane & 15)) * 64 + kk * 32 + (lane >> 4) * 8);
#pragma unroll
      for (int nr = 0; nr < 7; ++nr) {
        bf16x8 b = *(const bf16x8*)(B_s + (16 * nr + (lane & 15)) * 64 + kk * 32 + (lane >> 4) * 8);
        acc[nr] = __builtin_amdgcn_mfma_f32_16x16x32_bf16(a, b, acc[nr], 0, 0, 0);
      }
    }
    __syncthreads();
  }

#pragma unroll
  for (int nr = 0; nr < 7; ++nr) {
    int c = nr * 16 + (lane & 15);
#pragma unroll
    for (int reg = 0; reg < 4; ++reg) {
      int tl = 16 * wave + 4 * (lane >> 4) + reg;
      float wgt = (c < 16) ? 1.f : G[tl][(c - 16) >> 4];
      xh[(m0 + tl) * KDIM + 2048 + c] = __float2bfloat16(acc[nr][reg] * wgt);
    }
  }
  { // zero pad cols 112..127
    int c = 112 + (lane & 15);
#pragma unroll
    for (int reg = 0; reg < 4; ++reg) {
      int tl = 16 * wave + 4 * (lane >> 4) + reg;
      xh[(m0 + tl) * KDIM + 2048 + c] = __float2bfloat16(0.f);
    }
  }
}

// ---------------- kernel B: 256x256 tile, BK=32, 4-deep pipelined, swizzled-LDS GEMM ----------------
// out = xh @ Wcat^T + b_base   (K = 2176 covers base + LoRA correction)

__global__ __launch_bounds__(512, 2) void gemm256_kernel(
    const bf16* __restrict__ xh, const bf16* __restrict__ Wcat,
    const float* __restrict__ b_base, float* __restrict__ out) {
  extern __shared__ char sm[];
  int tid = threadIdx.x, wave = tid >> 6, lane = tid & 63;
  int wr = wave >> 2, wc = wave & 3;   // 2 x 4 wave grid; per-wave 128 x 64 output

  // XCD-bijective swizzle (nwg = 512, divisible by 8); consecutive swz share A panel
  int bid = blockIdx.x;
  int cpx = gridDim.x >> 3;
  int swz = (bid & 7) * cpx + (bid >> 3);
  long m0 = (long)(swz >> 3) * 256;
  int n0 = (swz & 7) * 256;

  // per-thread swizzled col-byte constant for frag ds_reads:
  // logical colByte = (lane>>4)<<4 ; swizzle XOR = ((row>>1)&3)<<4, row&15 == lane&15
  int cp = (((lane >> 4) << 4)) ^ ((((lane >> 1) & 3)) << 4);
  int arow = (wr * 128 + (lane & 15)) * 64;   // byte base within A tile (64B rows)
  int brow = (wc * 64 + (lane & 15)) * 64;

  float bias[4];
#pragma unroll
  for (int nr = 0; nr < 4; ++nr) bias[nr] = b_base[n0 + wc * 64 + nr * 16 + (lane & 15)];

  f32x4 acc[8][4];
#pragma unroll
  for (int i = 0; i < 8; ++i)
#pragma unroll
    for (int j = 0; j < 4; ++j) acc[i][j] = f32x4{0.f, 0.f, 0.f, 0.f};

  const bf16* Agl = xh + m0 * KDIM;
  const bf16* Bgl = Wcat + (long)n0 * KDIM;

  // stage one K-tile's A (or B) half: 256 rows x 32 cols bf16 = 16KB = 1024 chunks, 2/thread
  auto stageA = [&](int t2) {
    char* dst = sm + (t2 & 3) * 32768;
    const bf16* g = Agl + (long)t2 * 32;
#pragma unroll
    for (int k = 0; k < 2; ++k) {
      int cbase = k * 512 + wave * 64;
      int c = cbase + lane;
      int row = c >> 2;
      int scol = ((((c & 3) << 4) ^ ((((row >> 1) & 3)) << 4)) >> 1);
      __builtin_amdgcn_global_load_lds((const AS1 void*)(g + (long)row * KDIM + scol),
                                       (AS3 void*)(dst + cbase * 16), 16, 0, 0);
    }
  };
  auto stageB = [&](int t2) {
    char* dst = sm + (t2 & 3) * 32768 + 16384;
    const bf16* g = Bgl + (long)t2 * 32;
#pragma unroll
    for (int k = 0; k < 2; ++k) {
      int cbase = k * 512 + wave * 64;
      int c = cbase + lane;
      int row = c >> 2;
      int scol = ((((c & 3) << 4) ^ ((((row >> 1) & 3)) << 4)) >> 1);
      __builtin_amdgcn_global_load_lds((const AS1 void*)(g + (long)row * KDIM + scol),
                                       (AS3 void*)(dst + cbase * 16), 16, 0, 0);
    }
  };

  // prologue: stage K-tiles 0,1,2 (12 loads); wait until t0 resident (8 newest in flight)
  stageA(0); stageB(0);
  stageA(1); stageB(1);
  stageA(2); stageB(2);
  asm volatile("s_waitcnt vmcnt(8)" ::: "memory");
  __builtin_amdgcn_s_barrier();

  for (int t = 0; t < NT; ++t) {
    char* As_t = sm + (t & 3) * 32768;
    char* Bs_t = As_t + 16384;

    // ---- phase A: B frags + A frags mr 0..3, stage A(t+3), 16 MFMA ----
    bf16x8 bfr[4], a0[4];
#pragma unroll
    for (int nr = 0; nr < 4; ++nr)
      bfr[nr] = *(const bf16x8*)(Bs_t + brow + nr * 1024 + cp);
#pragma unroll
    for (int mh = 0; mh < 4; ++mh)
      a0[mh] = *(const bf16x8*)(As_t + arow + mh * 1024 + cp);
    if (t + 3 < NT) stageA(t + 3);
    __builtin_amdgcn_sched_barrier(0);
    __builtin_amdgcn_s_barrier();
    __builtin_amdgcn_sched_barrier(0);
    __builtin_amdgcn_s_setprio(1);
#pragma unroll
    for (int mh = 0; mh < 4; ++mh)
#pragma unroll
      for (int nr = 0; nr < 4; ++nr)
        acc[mh][nr] = __builtin_amdgcn_mfma_f32_16x16x32_bf16(a0[mh], bfr[nr], acc[mh][nr], 0, 0, 0);
    __builtin_amdgcn_s_setprio(0);
    __builtin_amdgcn_sched_barrier(0);
    __builtin_amdgcn_s_barrier();

    // ---- phase B: A frags mr 4..7, stage B(t+3), 16 MFMA ----
    bf16x8 a1[4];
#pragma unroll
    for (int mh = 0; mh < 4; ++mh)
      a1[mh] = *(const bf16x8*)(As_t + arow + (4 + mh) * 1024 + cp);
    if (t + 3 < NT) stageB(t + 3);
    __builtin_amdgcn_sched_barrier(0);
    __builtin_amdgcn_s_barrier();
    __builtin_amdgcn_sched_barrier(0);
    __builtin_amdgcn_s_setprio(1);
#pragma unroll
    for (int mh = 0; mh < 4; ++mh)
#pragma unroll
      for (int nr = 0; nr < 4; ++nr)
        acc[4 + mh][nr] = __builtin_amdgcn_mfma_f32_16x16x32_bf16(a1[mh], bfr[nr], acc[4 + mh][nr], 0, 0, 0);
    __builtin_amdgcn_s_setprio(0);
    // counted vmcnt: ensure t+1 resident; keep t+2/t+3 loads in flight (never drain mid-loop)
    if (t < NT - 3)      asm volatile("s_waitcnt vmcnt(8)" ::: "memory");
    else if (t == NT - 3) asm volatile("s_waitcnt vmcnt(4)" ::: "memory");
    else if (t == NT - 2) asm volatile("s_waitcnt vmcnt(0)" ::: "memory");
    __builtin_amdgcn_sched_barrier(0);
    __builtin_amdgcn_s_barrier();
  }

  // ---- epilogue: bias add, swizzled LDS repack (2 passes of 128KB), coalesced float4 stores ----
#pragma unroll
  for (int p = 0; p < 2; ++p) {
    if (p) __syncthreads();
    float* Creg = (float*)(sm + wave * 16384);
#pragma unroll
    for (int mh = 0; mh < 4; ++mh) {
      int mr = p * 4 + mh;
#pragma unroll
      for (int nr = 0; nr < 4; ++nr)
#pragma unroll
        for (int reg = 0; reg < 4; ++reg) {
          int row = mh * 16 + (lane >> 4) * 4 + reg;
          int col = nr * 16 + (lane & 15);
          Creg[row * 64 + (col ^ (((row >> 2) & 3) << 2))] = acc[mr][nr][reg] + bias[nr];
        }
    }
    __syncthreads();
#pragma unroll 4
    for (int q = tid; q < 8192; q += 512) {
      int rr = q >> 6;                 // 0..127 packed row
      int c4 = (q & 63) << 2;          // 0..252 col
      long gr = m0 + (rr >> 6) * 128 + p * 64 + (rr & 63);
      const float* srcw = (const float*)(sm + ((rr >> 6) * 4 + (c4 >> 6)) * 16384);
      int lcol = (c4 & 63) ^ ((((rr & 63) >> 2) & 3) << 2);
      f32x4 v = *(const f32x4*)(srcw + (rr & 63) * 64 + lcol);
      *(f32x4*)(out + gr * DDIM + n0 + c4) = v;
    }
  }
}

// ---------------- launcher ----------------

extern "C" void kernel_launch(void* const* d_in, const int* in_sizes, int n_in,
                              void* d_out, int out_size, void* d_ws, size_t ws_size,
                              hipStream_t stream) {
  const float* x        = (const float*)d_in[0];
  const float* W_base   = (const float*)d_in[1];
  const float* b_base   = (const float*)d_in[2];
  const float* A_s      = (const float*)d_in[3];
  const float* B_s      = (const float*)d_in[4];
  const float* A_r      = (const float*)d_in[5];
  const float* B_r      = (const float*)d_in[6];
  const float* W_router = (const float*)d_in[7];
  const float* b_router = (const float*)d_in[8];
  float* out = (float*)d_out;

  char* ws = (char*)d_ws;
  bf16*  xh    = (bf16*)(ws);                    // 16384*2176*2 = 71,303,168 B
  bf16*  Wcat  = (bf16*)(ws + 71303168);         //  2048*2176*2 =  8,912,896 B
  bf16*  AcT   = (bf16*)(ws + 80216064);         //   128*2048*2 =    524,288 B
  float* gates = (float*)(ws + 80740352);        //   16384*6*4  =    393,216 B  (total ~81.1 MB)

  (void)hipFuncSetAttribute((const void*)gemm256_kernel,
                            hipFuncAttributeMaxDynamicSharedMemorySize, 131072);

  conv_router_kernel<<<TTOK, 256, 0, stream>>>(x, W_router, b_router, xh, gates);
  convert_WT_kernel<<<1024, 256, 0, stream>>>(W_base, Wcat);
  build_AcatT<<<1024, 256, 0, stream>>>(A_s, A_r, AcT);
  build_BcatT<<<1024, 256, 0, stream>>>(B_s, B_r, Wcat);
  lora_kernel<<<256, 256, 0, stream>>>(xh, AcT, gates);
  gemm256_kernel<<<512, 512, 131072, stream>>>(xh, Wcat, b_base, out);
}